// Round 8
// baseline (313.814 us; speedup 1.0000x reference)
//
#include <hip/hip_runtime.h>

#define DIM 1024
#define BATCH 4
#define SEQ 4096
#define NH 16
#define HD 64
#define KP 256

typedef float f32x4 __attribute__((ext_vector_type(4)));
typedef _Float16 half8 __attribute__((ext_vector_type(8)));
typedef _Float16 half4v __attribute__((ext_vector_type(4)));
typedef int i32x4 __attribute__((ext_vector_type(4)));

__device__ __forceinline__ void gll16(const void* g, void* l) {
  __builtin_amdgcn_global_load_lds(
      (const __attribute__((address_space(1))) void*)g,
      (__attribute__((address_space(3))) void*)l, 16, 0, 0);
}

__device__ __forceinline__ unsigned lds_addr(const void* p) {
  return (unsigned)(size_t)(const __attribute__((address_space(3))) void*)p;
}

// asm ds_read_b128: opaque to alias analysis (round-3/4 lesson: compiler
// otherwise orders LDS reads against in-flight gll16 with vmcnt(0) drains).
#define DSR128(dst, base, imm)                                               \
  asm volatile("ds_read_b128 %0, %1 offset:" #imm : "=&v"(dst) : "v"(base))

#define BARR __builtin_amdgcn_s_barrier()
#define LGKM0                                                                \
  do {                                                                       \
    asm volatile("s_waitcnt lgkmcnt(0)" ::: "memory");                       \
    __builtin_amdgcn_sched_barrier(0);                                       \
  } while (0)
#define VMC(n) asm volatile("s_waitcnt vmcnt(" #n ")" ::: "memory")

// DPP row_ror:n within 16-lane rows. ctrl = 0x120|n.
#define DPPF(v, ctrl)                                                        \
  __builtin_bit_cast(float, __builtin_amdgcn_mov_dpp(                        \
                                __builtin_bit_cast(int, v), ctrl, 0xF, 0xF, true))

// ---- k_pre: xsum init + F transpose + Wq/Wo converts, one launch ----
__global__ void k_pre(const float* __restrict__ Wq, const float* __restrict__ Wo,
                      const float* __restrict__ F, _Float16* __restrict__ Wq_h,
                      _Float16* __restrict__ Wo_h, _Float16* __restrict__ Ft,
                      float* __restrict__ xsum) {
  int bb = blockIdx.x;
  if (bb < 16) {
    xsum[bb * 256 + threadIdx.x] = 0.f;
  } else if (bb < 80) {
    int i = (bb - 16) * 256 + threadIdx.x;  // 16384
    int k = i >> 6, d = i & 63;
    Ft[d * KP + (k & 15) * 16 + (k >> 4)] = (_Float16)F[i];
  } else {
    int b2 = bb - 80;
    const float* s = (b2 < 512) ? Wq : Wo;
    _Float16* d = (b2 < 512) ? Wq_h : Wo_h;
    int i = ((b2 & 511) * 256 + threadIdx.x) * 8;
    f32x4 a = *(const f32x4*)(s + i);
    f32x4 b = *(const f32x4*)(s + i + 4);
    half8 h;
    h[0] = a[0]; h[1] = a[1]; h[2] = a[2]; h[3] = a[3];
    h[4] = b[0]; h[5] = b[1]; h[6] = b[2]; h[7] = b[3];
    *(half8*)(d + i) = h;
  }
}

// ---- k_xcvt: fused fp32->fp16 convert + column-sum (one x pass) ----
// grid (128, BATCH); block = 32 rows x 1024 cols; thread owns 4 channels.
__global__ void k_xcvt(const float* __restrict__ x, _Float16* __restrict__ xh,
                       float* __restrict__ xs) {
  const int b = blockIdx.y, r0 = blockIdx.x * 32;
  const int c0 = threadIdx.x * 4;
  const float* p = x + ((size_t)(b * SEQ + r0)) * DIM + c0;
  _Float16* q = xh + ((size_t)(b * SEQ + r0)) * DIM + c0;
  float s0 = 0.f, s1 = 0.f, s2 = 0.f, s3 = 0.f;
  #pragma unroll 4
  for (int i = 0; i < 32; i++) {
    f32x4 v = *(const f32x4*)(p + (size_t)i * DIM);
    s0 += v[0]; s1 += v[1]; s2 += v[2]; s3 += v[3];
    half4v hv;
    hv[0] = (_Float16)v[0]; hv[1] = (_Float16)v[1];
    hv[2] = (_Float16)v[2]; hv[3] = (_Float16)v[3];
    *(half4v*)(q + (size_t)i * DIM) = hv;
  }
  float* xp = xs + b * DIM + c0;
  atomicAdd(xp + 0, s0);
  atomicAdd(xp + 1, s1);
  atomicAdd(xp + 2, s2);
  atomicAdd(xp + 3, s3);
}

// Sk[b,c] = xsum[b,:]@Wk[c,:], Sv likewise. One wave per output dot.
__global__ void k_sksv(const float* __restrict__ xs, const float* __restrict__ Wk,
                       const float* __restrict__ Wv, float* __restrict__ Sk,
                       float* __restrict__ Sv) {
  int idx = blockIdx.x * 4 + (threadIdx.x >> 6);
  int lane = threadIdx.x & 63;
  int kv = idx >> 12;
  int rem = idx & 4095;
  int b = rem >> 10, c = rem & 1023;
  const float* W = (kv ? Wv : Wk) + c * DIM;
  const float* xp = xs + b * DIM;
  float a = 0.f;
  #pragma unroll
  for (int i = 0; i < 16; i++) a += xp[lane + i * 64] * W[lane + i * 64];
  for (int off = 32; off; off >>= 1) a += __shfl_down(a, off);
  if (lane == 0) (kv ? Sv : Sk)[rem] = a;
}

// ---- fp16 MFMA GEMM, round 10: gll16 + ring-3 + depth-2 + 3 blocks/CU ----
// The untested combination from the per-CU DS audit: gll16 staging (LDS
// write rides the VMEM return path — no wave ds_write issue slots, unlike
// reg-staging's +192 cyc/tile), asm ds_read fragments (no alias drains),
// ring-3 LDS (48KB -> 3 blocks/CU co-resident to fill stall windows, m114),
// 2-tile prefetch depth (~1200 cyc cover > 900 cyc HBM latency), counted
// vmcnt(4) once per tile (t+2's 4 loads stay in flight), 1 barrier/tile.
// Lifetimes: tile t reads slot t%3; stages t+2 into slot (t+2)%3, whose
// last reads (tile t-1) completed before t-1's end barrier.
// MODE 0: out fp16 = (fp16)acc            (Q proj; Sk-scale folded into attn)
// MODE 1: out fp32 = acc + sb[col]        (out proj + bias)
#define MF(X, Y, C)                                                          \
  __builtin_amdgcn_mfma_f32_16x16x32_f16(__builtin_bit_cast(half8, (X)),     \
                                         __builtin_bit_cast(half8, (Y)),     \
                                         (C), 0, 0, 0)

#define STAGE(RB, T)                                                         \
  do {                                                                       \
    gll16(Ag + (T) * 32, &sh[RB][0][sdst]);                                  \
    gll16(Ag + (T) * 32 + 64 * DIM, &sh[RB][0][sdst + 2048]);                \
    gll16(Bg + (T) * 32, &sh[RB][1][sdst]);                                  \
    gll16(Bg + (T) * 32 + 64 * DIM, &sh[RB][1][sdst + 2048]);                \
  } while (0)

// STEN: stage tile T+2 into slot SS. VM: 0 -> vmcnt(4), 1 -> vmcnt(0), 2 -> none
#define GT(T, SLOT, SS, STEN, VM)                                            \
  {                                                                          \
    const unsigned ab = a0 + (SLOT) * 16384u;                                \
    const unsigned bb = b0 + (SLOT) * 16384u;                                \
    i32x4 fa0, fa1, fa2, fa3, fb0, fb1, fb2, fb3;                            \
    DSR128(fb0, bb, 0); DSR128(fb1, bb, 1024);                               \
    DSR128(fb2, bb, 2048); DSR128(fb3, bb, 3072);                            \
    DSR128(fa0, ab, 0); DSR128(fa1, ab, 1024);                               \
    DSR128(fa2, ab, 2048); DSR128(fa3, ab, 3072);                            \
    if (STEN) { STAGE(SS, (T) + 2); }                                        \
    LGKM0;                                                                   \
    __builtin_amdgcn_s_setprio(1);                                           \
    acc[0][0] = MF(fa0, fb0, acc[0][0]); acc[0][1] = MF(fa0, fb1, acc[0][1]);\
    acc[0][2] = MF(fa0, fb2, acc[0][2]); acc[0][3] = MF(fa0, fb3, acc[0][3]);\
    acc[1][0] = MF(fa1, fb0, acc[1][0]); acc[1][1] = MF(fa1, fb1, acc[1][1]);\
    acc[1][2] = MF(fa1, fb2, acc[1][2]); acc[1][3] = MF(fa1, fb3, acc[1][3]);\
    acc[2][0] = MF(fa2, fb0, acc[2][0]); acc[2][1] = MF(fa2, fb1, acc[2][1]);\
    acc[2][2] = MF(fa2, fb2, acc[2][2]); acc[2][3] = MF(fa2, fb3, acc[2][3]);\
    acc[3][0] = MF(fa3, fb0, acc[3][0]); acc[3][1] = MF(fa3, fb1, acc[3][1]);\
    acc[3][2] = MF(fa3, fb2, acc[3][2]); acc[3][3] = MF(fa3, fb3, acc[3][3]);\
    __builtin_amdgcn_s_setprio(0);                                           \
    if ((VM) == 0) { VMC(4); } else if ((VM) == 1) { VMC(0); }               \
    BARR;                                                                    \
  }

template <int MODE>
__global__ __launch_bounds__(256, 3) void k_gemm(const _Float16* __restrict__ A,
                                                 const _Float16* __restrict__ Bw,
                                                 void* __restrict__ Cout,
                                                 const float* __restrict__ sb) {
  __shared__ _Float16 sh[3][2][4096];  // ring-3 x [A,B] x (128 rows x 32 k) = 48KB
  const int tid = threadIdx.x;
  const int w = tid >> 6, l = tid & 63;
  const int q4 = l >> 4, mm = l & 15;
  const int wm = w & 1, wn = w >> 1;
  const int m0 = blockIdx.x * 128, n0 = blockIdx.y * 128;
  f32x4 acc[4][4] = {};

  // gll16 staging: lane l of wave w -> row w*16+(l>>2), stored chunk l&3;
  // source pre-swizzled: LDS[row][c] = global[row][c ^ ((row>>1)&3)].
  const int schunk = ((l & 3) ^ ((l >> 3) & 3)) * 8;
  const _Float16* Ag = A + (size_t)(m0 + w * 16 + (l >> 2)) * DIM + schunk;
  const _Float16* Bg = Bw + (size_t)(n0 + w * 16 + (l >> 2)) * DIM + schunk;
  const int sdst = w * 512;
  // reader: global chunk q4 of frag row r stored at chunk q4 ^ ((r>>1)&3)
  // = q4 ^ ((mm>>1)&3) (row bases are multiples of 16). Conflict-free
  // (measured 0 since round 1).
  const int csw = (q4 ^ ((mm >> 1) & 3)) * 8;
  const unsigned shb = lds_addr(&sh[0][0][0]);
  const unsigned a0 = shb + (unsigned)(((wm * 64 + mm) * 32 + csw) * 2);
  const unsigned b0 = shb + 8192u + (unsigned)(((wn * 64 + mm) * 32 + csw) * 2);

  // prologue: tiles 0,1 -> slots 0,1; wait tile 0 (tile 1's 4 stay in flight)
  STAGE(0, 0);
  STAGE(1, 1);
  VMC(4);
  BARR;

  for (int tt = 0; tt < 30; tt += 3) {
    GT(tt + 0, 0, 2, 1, 0)
    GT(tt + 1, 1, 0, 1, 0)
    GT(tt + 2, 2, 1, 1, 0)
  }
  GT(30, 0, 0, 0, 1)
  GT(31, 1, 0, 0, 2)

  if (MODE == 0) {
    _Float16* Lh = (_Float16*)sh;  // [64][136] fp16 per phase (padded)
    #pragma unroll
    for (int p = 0; p < 2; p++) {
      if (wm == p) {
        #pragma unroll
        for (int nt = 0; nt < 4; nt++) {
          const int cl = wn * 64 + nt * 16 + mm;
          #pragma unroll
          for (int mt = 0; mt < 4; mt++) {
            const int rl = mt * 16 + q4 * 4;
            #pragma unroll
            for (int r = 0; r < 4; r++)
              Lh[(rl + r) * 136 + cl] = (_Float16)acc[mt][nt][r];
          }
        }
      }
      __syncthreads();
      const int row_l = tid >> 2, c0 = (tid & 3) * 32;
      _Float16* dst = (_Float16*)Cout + (size_t)(m0 + p * 64 + row_l) * DIM + n0 + c0;
      #pragma unroll
      for (int i = 0; i < 4; i++)
        *(half8*)(dst + i * 8) = *(half8*)(Lh + row_l * 136 + c0 + i * 8);
      __syncthreads();
    }
  } else {
    float* Lf = (float*)sh;  // [32][132] f32 per phase (padded)
    #pragma unroll
    for (int p = 0; p < 4; p++) {
      if (wm == (p >> 1)) {
        #pragma unroll
        for (int nt = 0; nt < 4; nt++) {
          const int cl = wn * 64 + nt * 16 + mm;
          const float s = sb[n0 + cl];
          #pragma unroll
          for (int mti = 0; mti < 2; mti++) {
            const int mt = (p & 1) * 2 + mti;
            const int rl = mt * 16 + q4 * 4 - (p & 1) * 32;
            #pragma unroll
            for (int r = 0; r < 4; r++)
              Lf[(rl + r) * 132 + cl] = acc[mt][nt][r] + s;
          }
        }
      }
      __syncthreads();
      const int row_l = tid >> 3, c0 = (tid & 7) * 16;
      float* dst = (float*)Cout + (size_t)(m0 + p * 32 + row_l) * DIM + n0 + c0;
      #pragma unroll
      for (int i = 0; i < 4; i++)
        *(f32x4*)(dst + i * 4) = *(f32x4*)(Lf + row_l * 132 + c0 + i * 4);
      __syncthreads();
    }
  }
}

// ---- fused attention: grid (8,64); Sk*0.125*log2e folded into E-load ----
__global__ __launch_bounds__(256) void k_attn(const _Float16* __restrict__ Q,
                                              const float* __restrict__ E,
                                              const _Float16* __restrict__ Ftp,
                                              const float* __restrict__ Sk,
                                              const float* __restrict__ Sv,
                                              _Float16* __restrict__ O) {
  __shared__ _Float16 Ps[4][16][264];
  const int tid = threadIdx.x;
  const int w = tid >> 6, lane = tid & 63;
  const int q4 = lane >> 4, mm = lane & 15;
  const int bh = blockIdx.y;
  const int b = bh >> 4, h = bh & 15;
  const int row_base = blockIdx.x * 512 + w * 128;  // 8 tiles of 16 rows

  // per-d scale: Sk[b, h*64+d] * 0.125 * log2e, folded into E fragments
  const float qsc = 0.125f * 1.44269504088896f;
  float skf[2][8];
  #pragma unroll
  for (int kk = 0; kk < 2; kk++) {
    f32x4 u = *(const f32x4*)(Sk + b * DIM + h * HD + kk * 32 + q4 * 8);
    f32x4 v = *(const f32x4*)(Sk + b * DIM + h * HD + kk * 32 + q4 * 8 + 4);
    #pragma unroll
    for (int j = 0; j < 4; j++) {
      skf[kk][j] = u[j] * qsc;
      skf[kk][j + 4] = v[j] * qsc;
    }
  }
  half8 ef[16][2];
  #pragma unroll
  for (int t = 0; t < 16; t++)
    #pragma unroll
    for (int kk = 0; kk < 2; kk++) {
      const float* ep = E + (t * 16 + mm) * HD + kk * 32 + q4 * 8;
      f32x4 e0 = *(const f32x4*)ep;
      f32x4 e1 = *(const f32x4*)(ep + 4);
      half8 hv;
      #pragma unroll
      for (int j = 0; j < 4; j++) {
        hv[j] = (_Float16)(e0[j] * skf[kk][j]);
        hv[j + 4] = (_Float16)(e1[j] * skf[kk][j + 4]);
      }
      ef[t][kk] = hv;
    }
  half8 ff[4][8];
  #pragma unroll
  for (int nt = 0; nt < 4; nt++)
    #pragma unroll
    for (int kk = 0; kk < 8; kk++)
      ff[nt][kk] = *(const half8*)(Ftp + (nt * 16 + mm) * KP + kk * 32 + q4 * 8);
  float sv[4];
  #pragma unroll
  for (int nt = 0; nt < 4; nt++) sv[nt] = Sv[b * DIM + h * HD + nt * 16 + mm];

  const _Float16* Qbase = Q + ((size_t)(b * SEQ + row_base + mm)) * DIM + h * HD + q4 * 8;
  half8 qa0 = *(const half8*)(Qbase);
  half8 qa1 = *(const half8*)(Qbase + 32);

  for (int tile = 0; tile < 8; tile++) {
    f32x4 acc[16] = {};
    #pragma unroll
    for (int t = 0; t < 16; t++)
      acc[t] = __builtin_amdgcn_mfma_f32_16x16x32_f16(qa0, ef[t][0], acc[t], 0, 0, 0);
    #pragma unroll
    for (int t = 0; t < 16; t++)
      acc[t] = __builtin_amdgcn_mfma_f32_16x16x32_f16(qa1, ef[t][1], acc[t], 0, 0, 0);
    half8 qn0, qn1;
    if (tile < 7) {
      const _Float16* Qn = Qbase + (size_t)(tile + 1) * 16 * DIM;
      qn0 = *(const half8*)(Qn);
      qn1 = *(const half8*)(Qn + 32);
    }
    float mx[4] = {-1e30f, -1e30f, -1e30f, -1e30f};
    #pragma unroll
    for (int t = 0; t < 16; t++)
      #pragma unroll
      for (int r = 0; r < 4; r++) mx[r] = fmaxf(mx[r], acc[t][r]);
    #pragma unroll
    for (int r = 0; r < 4; r++) {
      float m = mx[r];
      m = fmaxf(m, DPPF(m, 0x121));
      m = fmaxf(m, DPPF(m, 0x122));
      m = fmaxf(m, DPPF(m, 0x124));
      m = fmaxf(m, DPPF(m, 0x128));
      mx[r] = m;
    }
    float sm[4] = {0.f, 0.f, 0.f, 0.f};
    #pragma unroll
    for (int t = 0; t < 16; t++)
      #pragma unroll
      for (int r = 0; r < 4; r++) {
        float p = __builtin_amdgcn_exp2f(acc[t][r] - mx[r]);
        acc[t][r] = p;
        sm[r] += p;
      }
    #pragma unroll
    for (int r = 0; r < 4; r++) {
      float s = sm[r];
      s += DPPF(s, 0x121);
      s += DPPF(s, 0x122);
      s += DPPF(s, 0x124);
      s += DPPF(s, 0x128);
      sm[r] = 1.f / s;
    }
    #pragma unroll
    for (int r = 0; r < 4; r++) {
      half8 h0, h1;
      #pragma unroll
      for (int t = 0; t < 8; t++) h0[t] = (_Float16)acc[t][r];
      #pragma unroll
      for (int t = 0; t < 8; t++) h1[t] = (_Float16)acc[t + 8][r];
      *(half8*)&Ps[w][q4 * 4 + r][mm * 16] = h0;
      *(half8*)&Ps[w][q4 * 4 + r][mm * 16 + 8] = h1;
    }
    f32x4 acc2[4] = {};
    #pragma unroll
    for (int kk = 0; kk < 8; kk++) {
      half8 pa = *(const half8*)&Ps[w][mm][kk * 32 + q4 * 8];
      #pragma unroll
      for (int nt = 0; nt < 4; nt++)
        acc2[nt] = __builtin_amdgcn_mfma_f32_16x16x32_f16(pa, ff[nt][kk], acc2[nt], 0, 0, 0);
    }
    const int rw0 = row_base + tile * 16;
    #pragma unroll
    for (int nt = 0; nt < 4; nt++)
      #pragma unroll
      for (int r = 0; r < 4; r++)
        O[(size_t)(b * SEQ + rw0 + q4 * 4 + r) * DIM + h * HD + nt * 16 + mm] =
            (_Float16)(acc2[nt][r] * (sm[r] * sv[nt]));
    qa0 = qn0;
    qa1 = qn1;
  }
}

extern "C" void kernel_launch(void* const* d_in, const int* in_sizes, int n_in,
                              void* d_out, int out_size, void* d_ws, size_t ws_size,
                              hipStream_t stream) {
  (void)in_sizes; (void)n_in; (void)out_size; (void)ws_size;
  const float* x  = (const float*)d_in[0];
  const float* Wq = (const float*)d_in[1];
  const float* Wk = (const float*)d_in[2];
  const float* Wv = (const float*)d_in[3];
  const float* E  = (const float*)d_in[4];
  const float* F  = (const float*)d_in[5];
  const float* Wo = (const float*)d_in[6];
  const float* bo = (const float*)d_in[7];
  char* ws = (char*)d_ws;
  _Float16* x_h  = (_Float16*)(ws);
  _Float16* O_h  = (_Float16*)(ws);          // aliases x_h (dead after Q GEMM)
  _Float16* Q_h  = (_Float16*)(ws + 33554432);
  _Float16* Wq_h = (_Float16*)(ws + 67108864);
  _Float16* Wo_h = (_Float16*)(ws + 69206016);
  _Float16* Ft_h = (_Float16*)(ws + 71335936);
  float* xsum    = (float*)(ws + 71368704);
  float* Sk      = (float*)(ws + 71385088);
  float* Sv      = (float*)(ws + 71401472);
  float* out     = (float*)d_out;

  k_pre<<<1104, 256, 0, stream>>>(Wq, Wo, F, Wq_h, Wo_h, Ft_h, xsum);
  k_xcvt<<<dim3(128, BATCH), 256, 0, stream>>>(x, x_h, xsum);
  k_sksv<<<2048, 256, 0, stream>>>(xsum, Wk, Wv, Sk, Sv);
  k_gemm<0><<<dim3(128, 8), 256, 0, stream>>>(x_h, Wq_h, (void*)Q_h, nullptr);
  k_attn<<<dim3(8, 64), 256, 0, stream>>>(Q_h, E, Ft_h, Sk, Sv, O_h);
  k_gemm<1><<<dim3(128, 8), 256, 0, stream>>>(O_h, Wo_h, (void*)out, bo);
}